// Round 2
// baseline (4543.090 us; speedup 1.0000x reference)
//
#include <hip/hip_runtime.h>
#include <hip/hip_fp16.h>
#include <cstdint>

#define TT 128   // time steps (= bucket_size)
#define BB 128   // batch
#define II 512   // input dim
#define HH 512   // hidden dim
#define DD 1024  // I + H
#define NC 513   // H + 1
#define NPAD 520 // row pitch for lnXW / vbuf (f16)
#define NT 36    // n-tiles of 16 in GEMM (576 padded cols)
#define EPSL 1e-5f

typedef _Float16 h2v __attribute__((ext_vector_type(2)));
typedef _Float16 h8v __attribute__((ext_vector_type(8)));
typedef float    f4v __attribute__((ext_vector_type(4)));

__device__ __forceinline__ ushort f2h(float f){
  return __builtin_bit_cast(ushort, __float2half(f));
}
__device__ __forceinline__ float h2f(ushort s){
  return __half2float(__builtin_bit_cast(__half, s));
}
__device__ __forceinline__ float hsig(float x){
  return fminf(fmaxf(0.2f * x + 0.5f, 0.f), 1.f);
}
// tanh(x) = 1 - 2/(exp(2x)+1) via v_exp_f32 + v_rcp_f32 (~1e-6 abs err)
__device__ __forceinline__ float ftanh(float x){
  float e = __expf(2.f * x);
  return 1.f - 2.f * __builtin_amdgcn_rcpf(e + 1.f);
}

// ---------------- pre-pack W / U into MFMA B-fragment order (f16) ----------
// dst element idx = ((kc*NT + nt)*16 + ni)*8 + kl  holds  src[k=kc*8+kl][n=nt*16+ni]
__global__ void prepack_B(const float* __restrict__ src, ushort* __restrict__ dst){
  int idx = blockIdx.x * 256 + threadIdx.x;
  if (idx >= 128 * NT * 16 * 8) return;
  int kl = idx & 7;
  int ni = (idx >> 3) & 15;
  int nt = (idx >> 7) % NT;
  int kc = idx / (NT * 16 * 8);
  int k = kc * 8 + kl;
  int n = nt * 16 + ni;
  float v = (n < NC) ? src[k * NC + n] : 0.f;
  dst[idx] = f2h(v);
}

// ---------------- pre-pack U_hi (rows I..I+511) for the recurrence GEMV ----
// Upk4 uint idx = (kpg*512 + n)*4 + j holds f16 pair (U[I+8kpg+2j][n], U[I+8kpg+2j+1][n])
__global__ void prepack_Uhi(const float* __restrict__ U, uint* __restrict__ Upk4,
                            ushort* __restrict__ ucol){
  int idx = blockIdx.x * 256 + threadIdx.x;
  if (idx < 64 * 512 * 4){
    int j   = idx & 3;
    int n   = (idx >> 2) & 511;
    int kpg = idx >> 11;
    int k0  = II + 8 * kpg + 2 * j;
    ushort lo = f2h(U[(size_t)k0 * NC + n]);
    ushort hi = f2h(U[(size_t)(k0 + 1) * NC + n]);
    Upk4[idx] = (uint)lo | ((uint)hi << 16);
  }
  if (idx < 512) ucol[idx] = f2h(U[(size_t)(II + idx) * NC + (NC - 1)]);
}

// ---------------- fused GEMM (+ optional row-LayerNorm), f16 MFMA ----------
__global__ __launch_bounds__(1024) void gemm_ln(
    const float* __restrict__ A, int amode, int ksteps,
    const ushort* __restrict__ Bpk, ushort* __restrict__ out,
    int do_ln, const float* __restrict__ gam, const float* __restrict__ bet,
    const float* __restrict__ bias)
{
  __shared__ ushort As[64][40];
  __shared__ float red[4][4][16][2];
  int tid = threadIdx.x;
  int lane = tid & 63, wid = tid >> 6;
  int quad = lane >> 4, l16 = lane & 15;
  int wm = wid >> 2, wn = wid & 3;
  int blk = blockIdx.x;

  f4v acc[9];
#pragma unroll
  for (int i = 0; i < 9; i++) acc[i] = (f4v){0.f, 0.f, 0.f, 0.f};

  int arow = tid >> 4;
  int acp  = tid & 15;
  int r = blk * 64 + arow;
  const float* aptr;
  if (amode == 0){ int t = r >> 7, b = r & 127; aptr = A + ((size_t)(b * TT + t)) * II + acp * 2; }
  else           { aptr = A + (size_t)r * DD + acp * 2; }

  for (int ks = 0; ks < ksteps; ks++){
    __syncthreads();
    float2 a2 = *(const float2*)(aptr + ks * 32);
    uint pk = (uint)f2h(a2.x) | ((uint)f2h(a2.y) << 16);
    *(uint*)&As[arow][acp * 2] = pk;
    __syncthreads();
    h8v af = *(const h8v*)&As[wm * 16 + l16][quad * 8];
    int kc = ks * 4 + quad;
    const h8v* bp = (const h8v*)Bpk + (size_t)kc * (NT * 16) + l16;
#pragma unroll
    for (int i = 0; i < 9; i++){
      h8v bf = bp[(wn * 9 + i) * 16];
      acc[i] = __builtin_amdgcn_mfma_f32_16x16x32_f16(af, bf, acc[i], 0, 0, 0);
    }
  }

  int rowbase = blk * 64 + wm * 16 + quad * 4;
  if (do_ln){
    float s1[4], s2[4];
#pragma unroll
    for (int g = 0; g < 4; g++){
      float a = 0.f, q = 0.f;
#pragma unroll
      for (int i = 0; i < 9; i++){ float v = acc[i][g]; a += v; q += v * v; }
#pragma unroll
      for (int m = 1; m < 16; m <<= 1){ a += __shfl_xor(a, m, 64); q += __shfl_xor(q, m, 64); }
      s1[g] = a; s2[g] = q;
    }
    if (l16 == 0){
#pragma unroll
      for (int g = 0; g < 4; g++){
        red[wm][wn][quad * 4 + g][0] = s1[g];
        red[wm][wn][quad * 4 + g][1] = s2[g];
      }
    }
    __syncthreads();
#pragma unroll
    for (int g = 0; g < 4; g++){
      int rr = quad * 4 + g;
      float S1 = red[wm][0][rr][0] + red[wm][1][rr][0] + red[wm][2][rr][0] + red[wm][3][rr][0];
      float S2 = red[wm][0][rr][1] + red[wm][1][rr][1] + red[wm][2][rr][1] + red[wm][3][rr][1];
      float mean = S1 * (1.f / 513.f);
      float var  = S2 * (1.f / 513.f) - mean * mean;
      float inv  = 1.f / (sqrtf(var + EPSL) + EPSL);
      size_t rg = (size_t)(rowbase + g);
#pragma unroll
      for (int i = 0; i < 9; i++){
        int n = wn * 144 + i * 16 + l16;
        if (n < NC){
          float val = gam[n] * ((acc[i][g] - mean) * inv) + bet[n] + bias[n];
          out[rg * NPAD + n] = f2h(val);
        }
      }
    }
  } else {
#pragma unroll
    for (int g = 0; g < 4; g++){
      size_t rg = (size_t)(rowbase + g);
#pragma unroll
      for (int i = 0; i < 9; i++){
        int n = wn * 144 + i * 16 + l16;
        if (n < NC) out[rg * NPAD + n] = f2h(acc[i][g]);
      }
    }
  }
}

// ---------------- per-batch-row sequential recurrence ----------------------
// one block per batch row b; 512 threads; thread n owns column n (thread 0 also col 512)
// 3 barriers per timestep; gates computed redundantly on all threads;
// GEMV software-pipelined with an 8-deep rolling uint4 buffer (U is t-invariant).
__global__ __launch_bounds__(512, 2) void rnn_layer(
    int layer,
    const float* __restrict__ x,
    float* __restrict__ h_seq,
    const ushort* __restrict__ lnXW,
    ushort* __restrict__ vbuf,
    float* __restrict__ fkbuf,
    float* __restrict__ hvbuf,
    const uint* __restrict__ Upk4,
    const ushort* __restrict__ ucol,
    const int* __restrict__ mask,
    const float* __restrict__ gam1, const float* __restrict__ bet1,
    const float* __restrict__ bias,
    float* __restrict__ out)
{
  __shared__ ushort tanhvh[512];
  __shared__ float red[16];
  __shared__ float red2[8];
  __shared__ float shv0;
  __shared__ float fkp_l[TT + 1];
  __shared__ float hvp_l[TT];
  __shared__ unsigned char mkq[TT];

  int tid = threadIdx.x;
  int b = blockIdx.x;
  int lane = tid & 63, wid = tid >> 6;

  if (tid < TT){
    mkq[tid] = (unsigned char)(mask[b * TT + tid] > 0);
    if (layer == 0){ fkp_l[tid] = 0.f; hvp_l[tid] = 1.f; }
    else { fkp_l[tid] = fkbuf[tid * BB + b]; hvp_l[tid] = hvbuf[tid * BB + b]; }
  }
  if (tid == 0){ fkp_l[TT] = 0.f; shv0 = 0.f; }

  float vreg = 0.f, v512 = 0.f;
  float h_lo = 0.f, h_hi = 0.f;
  float fk_c = 0.f, hv_c = 0.f;
  float g1n = gam1[tid], b1n = bet1[tid];
  float g1_0 = gam1[0], b1_0 = bet1[0], b0r = bias[0];
  float g1_512 = 0.f, b1_512 = 0.f;
  if (tid == 0){ g1_512 = gam1[512]; b1_512 = bet1[512]; }
  ushort ucr = ucol[tid];

  // prime the U pipeline (addresses are t-invariant)
  const uint* up = Upk4 + tid * 4;
  uint4 ubuf[8];
#pragma unroll
  for (int i = 0; i < 8; i++) ubuf[i] = *(const uint4*)(up + (size_t)i * 2048);

  __syncthreads();

  for (int t = 0; t < TT; t++){
    size_t row = (size_t)(t * BB + b);
    // ---- phase 0: issue this step's independent loads early ----
    ushort lnxw_u  = lnXW[row * NPAD + tid];
    ushort lnxw0_u = lnXW[row * NPAD];
    ushort xu_u    = vbuf[row * NPAD + tid];
    float xlo, xhi;
    if (layer == 0){ xlo = x[((size_t)(b * TT + t)) * II + tid]; xhi = 0.f; }
    else { xlo = h_seq[row * DD + tid]; xhi = h_seq[row * DD + 512 + tid]; }
    ushort lnxw512_u = 0, xu512_u = 0;
    if (tid == 0){ lnxw512_u = lnXW[row * NPAD + 512]; xu512_u = vbuf[row * NPAD + 512]; }
    bool mk  = mkq[t] != 0;
    bool mk2 = (t > 0) && (mkq[t - 1] != 0) && !mk;

    // ---- phase 1: LN stats of v (v lives in registers) ----
    float a = vreg, q = vreg * vreg;
    if (tid == 0){ a += v512; q += v512 * v512; }
#pragma unroll
    for (int m = 1; m < 64; m <<= 1){
      a += __shfl_xor(a, m, 64);
      q += __shfl_xor(q, m, 64);
    }
    if (lane == 0){ red[wid] = a; red[8 + wid] = q; }
    __syncthreads();   // (A)
    float S = 0.f, Q = 0.f;
#pragma unroll
    for (int w = 0; w < 8; w++){ S += red[w]; Q += red[8 + w]; }
    float mean = S * (1.f / 513.f);
    float var  = Q * (1.f / 513.f) - mean * mean;
    float inv  = __builtin_amdgcn_rcpf(sqrtf(var + EPSL) + EPSL);

    // ---- phase 2: s = lnXW + LN(v); tanh; gates on ALL threads ----
    float v0bc = shv0;
    float sum2 = (vreg - mean) * inv * g1n + b1n;
    float s = h2f(lnxw_u) + sum2;
    float sum20 = (v0bc - mean) * inv * g1_0 + b1_0;
    float s0 = h2f(lnxw0_u) + sum20;
    if (tid != 0){
      tanhvh[tid - 1] = f2h(ftanh(s));
    } else {
      float s512 = h2f(lnxw512_u) + (v512 - mean) * inv * g1_512 + b1_512;
      tanhvh[511] = f2h(ftanh(s512));
    }
    float fkp_tm1 = fkp_l[t];
    float fkp     = fkp_l[t + 1];
    float hvp     = hvp_l[t];
    float fk_both = hsig(s0);
    float fk_t1   = hsig(sum20 + b0r);
    float fk = fkp_tm1 + (1.f - fkp_tm1) * (fk_c * fk_both + (1.f - fk_c) * fk_t1);
    if (mk2) fk = 0.f;
    float h_only = hv_c * fk * (fkp + (1.f - fkp) * (1.f - hvp));
    float x_only = hvp * (1.f - fkp) * (1.f - fk + fk * (1.f - hv_c));
    float both   = (1.f - fkp) * fk * hv_c * hvp;
    float hv = 1.f - (1.f - h_only) * (1.f - x_only) * (1.f - both);
    fk_c = mk ? fk : fk_c;
    hv_c = mk ? hv : hv_c;
    if (mk2) fk_c = 0.f;
    if (layer < 3 && tid == 0){ fkbuf[t * BB + b] = fk_c; hvbuf[t * BB + b] = hv_c; }
    __syncthreads();   // (B)

    // ---- phase 3: col-512 reduce (overlaps) + pipelined GEMV ----
    float th_next = h2f(tanhvh[tid]);          // tanh index tid (feeds h_hi & col512)
    float p512 = th_next * h2f(ucr);
#pragma unroll
    for (int m = 1; m < 64; m <<= 1) p512 += __shfl_xor(p512, m, 64);
    if (lane == 0) red2[wid] = p512;

    float y0 = 0.f, y1 = 0.f, y2 = 0.f, y3 = 0.f;
#pragma unroll
    for (int base = 0; base < 64; base += 8){
#pragma unroll
      for (int j = 0; j < 8; j++){
        uint4 uu = ubuf[j];
        int nxt = (base + 8 + j) & 63;                       // wraps into next t
        ubuf[j] = *(const uint4*)(up + (size_t)nxt * 2048);
        uint4 tt = *(const uint4*)&tanhvh[8 * (base + j)];
#if __has_builtin(__builtin_amdgcn_fdot2)
        y0 = __builtin_amdgcn_fdot2(__builtin_bit_cast(h2v, uu.x), __builtin_bit_cast(h2v, tt.x), y0, false);
        y1 = __builtin_amdgcn_fdot2(__builtin_bit_cast(h2v, uu.y), __builtin_bit_cast(h2v, tt.y), y1, false);
        y2 = __builtin_amdgcn_fdot2(__builtin_bit_cast(h2v, uu.z), __builtin_bit_cast(h2v, tt.z), y2, false);
        y3 = __builtin_amdgcn_fdot2(__builtin_bit_cast(h2v, uu.w), __builtin_bit_cast(h2v, tt.w), y3, false);
#else
        {
          h2v ua = __builtin_bit_cast(h2v, uu.x), ta = __builtin_bit_cast(h2v, tt.x);
          h2v ub = __builtin_bit_cast(h2v, uu.y), tb = __builtin_bit_cast(h2v, tt.y);
          h2v uc = __builtin_bit_cast(h2v, uu.z), tc = __builtin_bit_cast(h2v, tt.z);
          h2v ud = __builtin_bit_cast(h2v, uu.w), td = __builtin_bit_cast(h2v, tt.w);
          y0 = fmaf((float)ua[0], (float)ta[0], y0); y0 = fmaf((float)ua[1], (float)ta[1], y0);
          y1 = fmaf((float)ub[0], (float)tb[0], y1); y1 = fmaf((float)ub[1], (float)tb[1], y1);
          y2 = fmaf((float)uc[0], (float)tc[0], y2); y2 = fmaf((float)uc[1], (float)tc[1], y2);
          y3 = fmaf((float)ud[0], (float)td[0], y3); y3 = fmaf((float)ud[1], (float)td[1], y3);
        }
#endif
      }
    }
    __syncthreads();   // (C)

    // ---- phase 4: updates (all in registers) ----
    float y = (y0 + y1) + (y2 + y3);
    float nh_lo = h_only * h_lo + x_only * xlo;
    float nh_hi = h_only * h_hi + x_only * xhi + both * th_next;
    if (mk){ h_lo = nh_lo; h_hi = nh_hi; }
    float nv = h_only * vreg + x_only * h2f(xu_u) + both * y;
    if (mk) vreg = nv;
    if (layer < 3){
      vbuf[row * NPAD + tid] = f2h(vreg);
      h_seq[row * DD + tid] = h_lo;
      h_seq[row * DD + 512 + tid] = h_hi;
    }
    if (tid == 0){
      float y512 = 0.f;
#pragma unroll
      for (int w = 0; w < 8; w++) y512 += red2[w];
      float nv5 = h_only * v512 + x_only * h2f(xu512_u) + both * y512;
      if (mk) v512 = nv5;
      if (layer < 3) vbuf[row * NPAD + 512] = f2h(v512);
      shv0 = vreg;
    }
    if (layer == 3 && t == TT - 1) out[b * HH + tid] = h_hi;
    // no end-of-loop barrier needed: next write targets are separated by (A)/(B)
  }
}

extern "C" void kernel_launch(void* const* d_in, const int* in_sizes, int n_in,
                              void* d_out, int out_size, void* d_ws, size_t ws_size,
                              hipStream_t stream)
{
  (void)in_sizes; (void)n_in; (void)out_size; (void)ws_size;
  const float* x      = (const float*)d_in[0];
  const int*   mask   = (const int*)d_in[1];
  const float* W      = (const float*)d_in[2];
  const float* U      = (const float*)d_in[3];
  const float* bias   = (const float*)d_in[4];
  const float* gammas = (const float*)d_in[5];
  const float* betas  = (const float*)d_in[6];
  float* out = (float*)d_out;

  char* ws = (char*)d_ws;
  size_t off = 0;
  auto alloc = [&](size_t bytes) -> void* {
    void* p = ws + off;
    off += (bytes + 255) & ~(size_t)255;
    return p;
  };
  float*  h_seq = (float*) alloc((size_t)TT * BB * DD * 4);
  ushort* lnXW  = (ushort*)alloc((size_t)TT * BB * NPAD * 2);
  ushort* vbuf  = (ushort*)alloc((size_t)TT * BB * NPAD * 2);
  float*  fkbuf = (float*) alloc((size_t)TT * BB * 4);
  float*  hvbuf = (float*) alloc((size_t)TT * BB * 4);
  ushort* Wpk   = (ushort*)alloc((size_t)128 * NT * 16 * 8 * 2);
  ushort* Upk   = (ushort*)alloc((size_t)128 * NT * 16 * 8 * 2);
  uint*   Upk4  = (uint*)  alloc((size_t)64 * 512 * 4 * 4);
  ushort* ucol  = (ushort*)alloc(512 * 2);

  int npk = 128 * NT * 16 * 8;
  prepack_B<<<dim3((npk + 255) / 256), dim3(256), 0, stream>>>(W, Wpk);
  prepack_B<<<dim3((npk + 255) / 256), dim3(256), 0, stream>>>(U, Upk);
  prepack_Uhi<<<dim3((64 * 512 * 4 + 255) / 256), dim3(256), 0, stream>>>(U, Upk4, ucol);

  const float* g0 = gammas,      *g1 = gammas + NC;
  const float* be0 = betas,      *be1 = betas + NC;

  gemm_ln<<<dim3(256), dim3(1024), 0, stream>>>(x, 0, 16, Wpk, lnXW, 1, g0, be0, bias);
  gemm_ln<<<dim3(256), dim3(1024), 0, stream>>>(x, 0, 16, Upk, vbuf, 0, g0, be0, bias);
  rnn_layer<<<dim3(BB), dim3(512), 0, stream>>>(0, x, h_seq, lnXW, vbuf, fkbuf, hvbuf,
                                                Upk4, ucol, mask, g1, be1, bias, out);
  for (int d = 1; d < 4; d++){
    gemm_ln<<<dim3(256), dim3(1024), 0, stream>>>(h_seq, 1, 32, Wpk, lnXW, 1, g0, be0, bias);
    rnn_layer<<<dim3(BB), dim3(512), 0, stream>>>(d, x, h_seq, lnXW, vbuf, fkbuf, hvbuf,
                                                  Upk4, ucol, mask, g1, be1, bias, out);
  }
}